// Round 1
// baseline (722.805 us; speedup 1.0000x reference)
//
#include <hip/hip_runtime.h>

#define B_BATCH 8
#define SEQ 4096
#define D_MODEL 1024
#define D_STATE 64
#define EPS 1e-6f

#define T_CHUNK 512   // time steps per scan block (8 chunks)
#define WARM 64       // redundant warm-up steps; A<=0.7311 => 0.7311^64 ~ 2e-9
#define ROUND 32      // steps staged in LDS per round

__device__ __forceinline__ float sigmoidf(float v) {
    return 1.0f / (1.0f + __expf(-v));
}

// ---------------------------------------------------------------------------
// Kernel 0: apply sigmoids, transpose B_w to [D][N]
// ---------------------------------------------------------------------------
__global__ __launch_bounds__(256) void prep_kernel(
    const float* __restrict__ A_raw, const float* __restrict__ B_w,
    const float* __restrict__ C_w, const float* __restrict__ gamma,
    float* __restrict__ As, float* __restrict__ Bt, float* __restrict__ Cs,
    float* __restrict__ gs) {
    int i = blockIdx.x * 256 + threadIdx.x;   // 0 .. D*N-1
    int d = i >> 6;
    int n = i & 63;
    As[i] = sigmoidf(A_raw[i]);               // [D][N]
    Cs[i] = sigmoidf(C_w[i]);                 // [D][N]
    Bt[i] = sigmoidf(B_w[n * D_MODEL + d]);   // Bt[d][n] = sigmoid(B_w[n][d])
    if (n == 0) gs[d] = sigmoidf(gamma[d]);
}

// ---------------------------------------------------------------------------
// Kernel 1: U[row][n] = sum_d x[row][d] * Bt[d][n]   (row = b*SEQ + t)
// ---------------------------------------------------------------------------
__device__ __forceinline__ void fma4(float av, const float4 bv, float* acc) {
    acc[0] = fmaf(av, bv.x, acc[0]);
    acc[1] = fmaf(av, bv.y, acc[1]);
    acc[2] = fmaf(av, bv.z, acc[2]);
    acc[3] = fmaf(av, bv.w, acc[3]);
}

__global__ __launch_bounds__(256) void u_gemm_kernel(
    const float* __restrict__ x, const float* __restrict__ Bt,
    float* __restrict__ U) {
    __shared__ float xs[64 * 68];
    __shared__ float Bs[64 * 64];
    const int tid = threadIdx.x;
    const int row0 = blockIdx.x * 64;
    const int tr = tid >> 4;
    const int tc = tid & 15;
    float acc[4][4] = {};

    for (int d0 = 0; d0 < D_MODEL; d0 += 64) {
#pragma unroll
        for (int i = 0; i < 4; ++i) {
            int f4 = i * 1024 + tid * 4;
            int r = f4 >> 6, c = f4 & 63;
            float4 v = *(const float4*)&x[(size_t)(row0 + r) * D_MODEL + d0 + c];
            *(float4*)&xs[r * 68 + c] = v;
        }
#pragma unroll
        for (int i = 0; i < 4; ++i) {
            int f4 = i * 1024 + tid * 4;
            *(float4*)&Bs[f4] = *(const float4*)&Bt[d0 * 64 + f4];
        }
        __syncthreads();
#pragma unroll
        for (int dd = 0; dd < 64; dd += 4) {
            float4 b0 = *(const float4*)&Bs[(dd + 0) * 64 + tc * 4];
            float4 b1 = *(const float4*)&Bs[(dd + 1) * 64 + tc * 4];
            float4 b2 = *(const float4*)&Bs[(dd + 2) * 64 + tc * 4];
            float4 b3 = *(const float4*)&Bs[(dd + 3) * 64 + tc * 4];
#pragma unroll
            for (int i = 0; i < 4; ++i) {
                float4 a = *(const float4*)&xs[(tr * 4 + i) * 68 + dd];
                fma4(a.x, b0, acc[i]);
                fma4(a.y, b1, acc[i]);
                fma4(a.z, b2, acc[i]);
                fma4(a.w, b3, acc[i]);
            }
        }
        __syncthreads();
    }
#pragma unroll
    for (int i = 0; i < 4; ++i) {
        float4 v = make_float4(acc[i][0], acc[i][1], acc[i][2], acc[i][3]);
        *(float4*)&U[(size_t)(row0 + tr * 4 + i) * 64 + tc * 4] = v;
    }
}

// ---------------------------------------------------------------------------
// Kernel 2: time-split scan with SATURATION FAST PATH.
// Block = (b, 32-d chunk, t-chunk of 512). 8 lanes per d, 8 n/lane.
//
// Key algebra: h = clip(h*A + u_n*x_d, 0, 1) with all terms >= 0, so if
// x_d * min_n(u_t) >= 1 then h[d][:] == 1.0 EXACTLY regardless of history,
// and y_d = sum_n C[d][n] (precomputed crow). With the bench distribution
// (u ~ 256) this holds for ~99.6% of (d,t); per 8-d wave ~97% of steps.
// The check is made wave-uniform (scalar branch) by precomputing per-t
// min_n(U) and per-(wave,t) min_d(x) during LDS staging. h:=1 is deferred
// via the wave-uniform 'hone' flag so the fast path writes nothing but y.
// Fast path is exact: condition verified at runtime, so correctness does
// not depend on the data distribution (only speed does).
// ---------------------------------------------------------------------------
__global__ __launch_bounds__(256, 8) void scan_kernel(
    const float* __restrict__ x, const float* __restrict__ U,
    const float* __restrict__ As, const float* __restrict__ Cs,
    float* __restrict__ yraw, float* __restrict__ hout) {
    __shared__ float Ulds[ROUND * 64];    // 8 KB
    __shared__ float xlds[ROUND * 32];    // 4 KB
    __shared__ float ylds[ROUND * 32];    // 4 KB
    __shared__ float uminlds[ROUND];      // 128 B : min over n of U[t][:]
    __shared__ float xminlds[4 * ROUND];  // 512 B : [wave][t] min over wave's 8 d
    const int tid = threadIdx.x;
    const int c = blockIdx.x & 7;                 // t-chunk
    const int d0 = ((blockIdx.x >> 3) & 31) * 32; // d-chunk
    const int b = blockIdx.x >> 8;                // batch
    const int g = tid >> 3;   // 0..31 -> d = d0+g
    const int l = tid & 7;    // 0..7  -> n = l*8 .. l*8+7
    const int d = d0 + g;
    const int w = tid >> 6;   // wave id 0..3 (covers g in [8w, 8w+8))

    float h[8], a[8], cc[8];
    {
        float4 a0 = *(const float4*)&As[d * 64 + l * 8];
        float4 a1 = *(const float4*)&As[d * 64 + l * 8 + 4];
        a[0] = a0.x; a[1] = a0.y; a[2] = a0.z; a[3] = a0.w;
        a[4] = a1.x; a[5] = a1.y; a[6] = a1.z; a[7] = a1.w;
        float4 c0 = *(const float4*)&Cs[d * 64 + l * 8];
        float4 c1 = *(const float4*)&Cs[d * 64 + l * 8 + 4];
        cc[0] = c0.x; cc[1] = c0.y; cc[2] = c0.z; cc[3] = c0.w;
        cc[4] = c1.x; cc[5] = c1.y; cc[6] = c1.z; cc[7] = c1.w;
    }
    // crow = sum over all 64 n of C[d][n] (y value when h[d][:] == 1)
    float crow = ((cc[0] + cc[1]) + (cc[2] + cc[3])) +
                 ((cc[4] + cc[5]) + (cc[6] + cc[7]));
    crow += __shfl_xor(crow, 1);
    crow += __shfl_xor(crow, 2);
    crow += __shfl_xor(crow, 4);
#pragma unroll
    for (int j = 0; j < 8; ++j) h[j] = 0.0f;
    bool hone = false;   // wave-uniform: true => h[0..7] == 1.0 (deferred)

    const size_t xbase = (size_t)b * SEQ * D_MODEL;
    const size_t ubase = (size_t)b * SEQ * 64;
    const int t_main = c * T_CHUNK;
    const int t_begin = (c == 0) ? 0 : t_main - WARM;
    const int t_end = t_main + T_CHUNK;

    for (int t0 = t_begin; t0 < t_end; t0 += ROUND) {
        // ---- stage U round + per-t umin (from staging regs, pre-barrier) ----
        {
            const float* Up = &U[ubase + (size_t)t0 * 64];
            float4 v0 = *(const float4*)&Up[tid * 4];          // t = tid>>4
            float4 v1 = *(const float4*)&Up[1024 + tid * 4];   // t = 16+(tid>>4)
            *(float4*)&Ulds[tid * 4] = v0;
            *(float4*)&Ulds[1024 + tid * 4] = v1;
            float m0 = fminf(fminf(v0.x, v0.y), fminf(v0.z, v0.w));
            float m1 = fminf(fminf(v1.x, v1.y), fminf(v1.z, v1.w));
#pragma unroll
            for (int s = 1; s < 16; s <<= 1) {   // 16 lanes share each t
                m0 = fminf(m0, __shfl_xor(m0, s));
                m1 = fminf(m1, __shfl_xor(m1, s));
            }
            if ((tid & 15) == 0) {
                uminlds[tid >> 4] = m0;
                uminlds[(tid >> 4) + 16] = m1;
            }
        }
        // ---- stage x round + per-(wave,t) xmin ----
        {
            int f4 = tid * 4;
            int tt = f4 >> 5, dd = f4 & 31;
            float4 v =
                *(const float4*)&x[xbase + (size_t)(t0 + tt) * D_MODEL + d0 + dd];
            *(float4*)&xlds[f4] = v;
            float m = fminf(fminf(v.x, v.y), fminf(v.z, v.w));
            m = fminf(m, __shfl_xor(m, 1));   // pair covers one wave's 8 d
            if ((tid & 1) == 0) xminlds[((tid >> 1) & 3) * ROUND + tt] = m;
        }
        __syncthreads();

        const bool emit = (t0 >= t_main);
        if (emit) {
            for (int tq = 0; tq < ROUND; tq += 4) {
                float4 um4 = *(const float4*)&uminlds[tq];
                float4 xm4 = *(const float4*)&xminlds[w * ROUND + tq];
                float umv[4] = {um4.x, um4.y, um4.z, um4.w};
                float xmv[4] = {xm4.x, xm4.y, xm4.z, xm4.w};
#pragma unroll
                for (int k = 0; k < 4; ++k) {
                    const int tt = tq + k;
                    float p = xmv[k] * umv[k];
                    // p >= 0 always, so float>=1.0 compares as int bits.
                    // Operands are wave-uniform -> pure scalar branch.
                    if (__builtin_amdgcn_readfirstlane(__float_as_int(p)) >=
                        0x3f800000) {
                        hone = true;                    // h := all ones (deferred)
                        if (l == 0) ylds[tt * 32 + g] = crow;
                    } else {
                        if (hone) {
#pragma unroll
                            for (int j = 0; j < 8; ++j) h[j] = 1.0f;
                            hone = false;
                        }
                        float xt = xlds[tt * 32 + g];
                        float4 u0 = *(const float4*)&Ulds[tt * 64 + l * 8];
                        float4 u1 = *(const float4*)&Ulds[tt * 64 + l * 8 + 4];
                        float uu[8] = {u0.x, u0.y, u0.z, u0.w,
                                       u1.x, u1.y, u1.z, u1.w};
                        float y0 = 0.0f, y1 = 0.0f;
#pragma unroll
                        for (int j = 0; j < 4; ++j) {
                            h[j] = __builtin_amdgcn_fmed3f(
                                fmaf(h[j], a[j], uu[j] * xt), 0.0f, 1.0f);
                            y0 = fmaf(h[j], cc[j], y0);
                        }
#pragma unroll
                        for (int j = 4; j < 8; ++j) {
                            h[j] = __builtin_amdgcn_fmed3f(
                                fmaf(h[j], a[j], uu[j] * xt), 0.0f, 1.0f);
                            y1 = fmaf(h[j], cc[j], y1);
                        }
                        float y = y0 + y1;
                        y += __shfl_xor(y, 1);
                        y += __shfl_xor(y, 2);
                        y += __shfl_xor(y, 4);
                        if (l == 0) ylds[tt * 32 + g] = y;
                    }
                }
            }
        } else {
            // warm-up: advance h only, no y
            for (int tq = 0; tq < ROUND; tq += 4) {
                float4 um4 = *(const float4*)&uminlds[tq];
                float4 xm4 = *(const float4*)&xminlds[w * ROUND + tq];
                float umv[4] = {um4.x, um4.y, um4.z, um4.w};
                float xmv[4] = {xm4.x, xm4.y, xm4.z, xm4.w};
#pragma unroll
                for (int k = 0; k < 4; ++k) {
                    const int tt = tq + k;
                    float p = xmv[k] * umv[k];
                    if (__builtin_amdgcn_readfirstlane(__float_as_int(p)) >=
                        0x3f800000) {
                        hone = true;
                    } else {
                        if (hone) {
#pragma unroll
                            for (int j = 0; j < 8; ++j) h[j] = 1.0f;
                            hone = false;
                        }
                        float xt = xlds[tt * 32 + g];
                        float4 u0 = *(const float4*)&Ulds[tt * 64 + l * 8];
                        float4 u1 = *(const float4*)&Ulds[tt * 64 + l * 8 + 4];
                        float uu[8] = {u0.x, u0.y, u0.z, u0.w,
                                       u1.x, u1.y, u1.z, u1.w};
#pragma unroll
                        for (int j = 0; j < 8; ++j) {
                            h[j] = __builtin_amdgcn_fmed3f(
                                fmaf(h[j], a[j], uu[j] * xt), 0.0f, 1.0f);
                        }
                    }
                }
            }
        }
        __syncthreads();

        if (emit) {
            int f4 = tid * 4;
            int tt = f4 >> 5, dd = f4 & 31;
            *(float4*)&yraw[xbase + (size_t)(t0 + tt) * D_MODEL + d0 + dd] =
                *(const float4*)&ylds[f4];
        }
        // Ulds/xlds rewrite next round is fenced by the post-stage sync;
        // ylds flush-read vs next compute-write is fenced the same way.
    }

    if (c == (SEQ / T_CHUNK) - 1) {
        if (hone) {
#pragma unroll
            for (int j = 0; j < 8; ++j) h[j] = 1.0f;
        }
        float4 h0 = make_float4(h[0], h[1], h[2], h[3]);
        float4 h1 = make_float4(h[4], h[5], h[6], h[7]);
        size_t hoff = ((size_t)b * D_MODEL + d) * 64 + l * 8;
        *(float4*)&hout[hoff] = h0;
        *(float4*)&hout[hoff + 4] = h1;
    }
}

// ---------------------------------------------------------------------------
// Kernel 3: in-place normalize: out = clip(g*y/(sum_d y + eps) + x, 0, 1)
// ---------------------------------------------------------------------------
__global__ __launch_bounds__(256) void norm_kernel(
    const float* __restrict__ x, const float* __restrict__ gs,
    float* __restrict__ y) {
    __shared__ float red[4];
    const int tid = threadIdx.x;
    const size_t base = (size_t)blockIdx.x * D_MODEL;

    float4 yv = *(const float4*)&y[base + tid * 4];
    float s = yv.x + yv.y + yv.z + yv.w;
#pragma unroll
    for (int off = 1; off < 64; off <<= 1) s += __shfl_xor(s, off);
    if ((tid & 63) == 0) red[tid >> 6] = s;
    __syncthreads();
    float tot = red[0] + red[1] + red[2] + red[3];
    float inv = 1.0f / (tot + EPS);

    float4 xv = *(const float4*)&x[base + tid * 4];
    float4 gv = *(const float4*)&gs[tid * 4];
    float4 o;
    o.x = __builtin_amdgcn_fmed3f(fmaf(gv.x * yv.x, inv, xv.x), 0.0f, 1.0f);
    o.y = __builtin_amdgcn_fmed3f(fmaf(gv.y * yv.y, inv, xv.y), 0.0f, 1.0f);
    o.z = __builtin_amdgcn_fmed3f(fmaf(gv.z * yv.z, inv, xv.z), 0.0f, 1.0f);
    o.w = __builtin_amdgcn_fmed3f(fmaf(gv.w * yv.w, inv, xv.w), 0.0f, 1.0f);
    *(float4*)&y[base + tid * 4] = o;
}

// ---------------------------------------------------------------------------
extern "C" void kernel_launch(void* const* d_in, const int* in_sizes, int n_in,
                              void* d_out, int out_size, void* d_ws,
                              size_t ws_size, hipStream_t stream) {
    const float* x     = (const float*)d_in[0];
    const float* A_raw = (const float*)d_in[1];
    const float* B_w   = (const float*)d_in[2];
    const float* C_w   = (const float*)d_in[3];
    const float* gamma = (const float*)d_in[4];

    float* out  = (float*)d_out;
    float* yout = out;                                      // [B,S,D]
    float* hout = out + (size_t)B_BATCH * SEQ * D_MODEL;    // [B,D,N]

    float* ws = (float*)d_ws;
    float* As = ws;                  // 65536
    float* Bt = ws + 65536;          // 65536
    float* Cs = ws + 131072;         // 65536
    float* gs = ws + 196608;         // 1024
    float* U  = ws + 197632;         // B*SEQ*64 = 2097152

    prep_kernel<<<256, 256, 0, stream>>>(A_raw, B_w, C_w, gamma, As, Bt, Cs, gs);
    u_gemm_kernel<<<(B_BATCH * SEQ) / 64, 256, 0, stream>>>(x, Bt, U);
    scan_kernel<<<B_BATCH * (D_MODEL / 32) * (SEQ / T_CHUNK), 256, 0, stream>>>(
        x, U, As, Cs, yout, hout);
    norm_kernel<<<B_BATCH * SEQ, 256, 0, stream>>>(x, gs, yout);
}

// Round 2
// 586.393 us; speedup vs baseline: 1.2326x; 1.2326x over previous
//
#include <hip/hip_runtime.h>

#define B_BATCH 8
#define SEQ 4096
#define D_MODEL 1024
#define D_STATE 64
#define EPS 1e-6f

#define T_CHUNK 512   // time steps per scan block (8 chunks)
#define WARM 64       // redundant warm-up steps; A<=0.7311 => 0.7311^64 ~ 2e-9
#define ROUND 32      // steps staged in LDS per round

typedef float v2f __attribute__((ext_vector_type(2)));

__device__ __forceinline__ float sigmoidf(float v) {
    return 1.0f / (1.0f + __expf(-v));
}

// ---------------------------------------------------------------------------
// Kernel 0: apply sigmoids, transpose B_w to [D][N]
// ---------------------------------------------------------------------------
__global__ __launch_bounds__(256) void prep_kernel(
    const float* __restrict__ A_raw, const float* __restrict__ B_w,
    const float* __restrict__ C_w, const float* __restrict__ gamma,
    float* __restrict__ As, float* __restrict__ Bt, float* __restrict__ Cs,
    float* __restrict__ gs) {
    int i = blockIdx.x * 256 + threadIdx.x;   // 0 .. D*N-1
    int d = i >> 6;
    int n = i & 63;
    As[i] = sigmoidf(A_raw[i]);               // [D][N]
    Cs[i] = sigmoidf(C_w[i]);                 // [D][N]
    Bt[i] = sigmoidf(B_w[n * D_MODEL + d]);   // Bt[d][n] = sigmoid(B_w[n][d])
    if (n == 0) gs[d] = sigmoidf(gamma[d]);
}

// ---------------------------------------------------------------------------
// Kernel 1: U[row][n] = sum_d x[row][d] * Bt[d][n]   (row = b*SEQ + t)
// ---------------------------------------------------------------------------
__device__ __forceinline__ void fma4(float av, const float4 bv, float* acc) {
    acc[0] = fmaf(av, bv.x, acc[0]);
    acc[1] = fmaf(av, bv.y, acc[1]);
    acc[2] = fmaf(av, bv.z, acc[2]);
    acc[3] = fmaf(av, bv.w, acc[3]);
}

__global__ __launch_bounds__(256) void u_gemm_kernel(
    const float* __restrict__ x, const float* __restrict__ Bt,
    float* __restrict__ U) {
    __shared__ float xs[64 * 68];
    __shared__ float Bs[64 * 64];
    const int tid = threadIdx.x;
    const int row0 = blockIdx.x * 64;
    const int tr = tid >> 4;
    const int tc = tid & 15;
    float acc[4][4] = {};

    for (int d0 = 0; d0 < D_MODEL; d0 += 64) {
#pragma unroll
        for (int i = 0; i < 4; ++i) {
            int f4 = i * 1024 + tid * 4;
            int r = f4 >> 6, c = f4 & 63;
            float4 v = *(const float4*)&x[(size_t)(row0 + r) * D_MODEL + d0 + c];
            *(float4*)&xs[r * 68 + c] = v;
        }
#pragma unroll
        for (int i = 0; i < 4; ++i) {
            int f4 = i * 1024 + tid * 4;
            *(float4*)&Bs[f4] = *(const float4*)&Bt[d0 * 64 + f4];
        }
        __syncthreads();
#pragma unroll
        for (int dd = 0; dd < 64; dd += 4) {
            float4 b0 = *(const float4*)&Bs[(dd + 0) * 64 + tc * 4];
            float4 b1 = *(const float4*)&Bs[(dd + 1) * 64 + tc * 4];
            float4 b2 = *(const float4*)&Bs[(dd + 2) * 64 + tc * 4];
            float4 b3 = *(const float4*)&Bs[(dd + 3) * 64 + tc * 4];
#pragma unroll
            for (int i = 0; i < 4; ++i) {
                float4 a = *(const float4*)&xs[(tr * 4 + i) * 68 + dd];
                fma4(a.x, b0, acc[i]);
                fma4(a.y, b1, acc[i]);
                fma4(a.z, b2, acc[i]);
                fma4(a.w, b3, acc[i]);
            }
        }
        __syncthreads();
    }
#pragma unroll
    for (int i = 0; i < 4; ++i) {
        float4 v = make_float4(acc[i][0], acc[i][1], acc[i][2], acc[i][3]);
        *(float4*)&U[(size_t)(row0 + tr * 4 + i) * 64 + tc * 4] = v;
    }
}

// ---------------------------------------------------------------------------
// Kernel 2: time-split scan. Block = (b, 32-d chunk, t-chunk of 512).
// 8 lanes per d, 8 n/lane held as 4 float2 pairs so the state update issues
// as v_pk_mul_f32 / v_pk_fma_f32 (2 fp32 ops per VALU slot on CDNA4).
// Control flow is intentionally data-INDEPENDENT: uniform per-round progress
// is what keeps the 32 blocks sharing each U t-range in lockstep so L3
// absorbs the 32x U reuse (round-1 lesson: a data-dependent fast path
// desynced blocks and blew FETCH 88->644 MB).
// Each t-chunk (except the first) redundantly recomputes WARM steps from
// h=0; contraction (A<=0.7311) kills the error.
// Emits UNNORMALIZED y into yraw; last chunk emits h_final.
// ---------------------------------------------------------------------------
__global__ __launch_bounds__(256, 8) void scan_kernel(
    const float* __restrict__ x, const float* __restrict__ U,
    const float* __restrict__ As, const float* __restrict__ Cs,
    float* __restrict__ yraw, float* __restrict__ hout) {
    __shared__ float Ulds[ROUND * 64];   // 8 KB
    __shared__ float xlds[ROUND * 32];   // 4 KB
    __shared__ float ylds[ROUND * 32];   // 4 KB
    const int tid = threadIdx.x;
    const int c = blockIdx.x & 7;                 // t-chunk
    const int d0 = ((blockIdx.x >> 3) & 31) * 32; // d-chunk
    const int b = blockIdx.x >> 8;                // batch
    const int g = tid >> 3;   // 0..31 -> d = d0+g
    const int l = tid & 7;    // 0..7  -> n = l*8 .. l*8+7
    const int d = d0 + g;

    v2f h2[4], a2[4], c2[4];
    {
        const v2f* ap = (const v2f*)&As[d * 64 + l * 8];
        const v2f* cp = (const v2f*)&Cs[d * 64 + l * 8];
#pragma unroll
        for (int jp = 0; jp < 4; ++jp) {
            a2[jp] = ap[jp];
            c2[jp] = cp[jp];
            h2[jp] = (v2f){0.0f, 0.0f};
        }
    }

    const size_t xbase = (size_t)b * SEQ * D_MODEL;
    const size_t ubase = (size_t)b * SEQ * 64;
    const int t_main = c * T_CHUNK;
    const int t_begin = (c == 0) ? 0 : t_main - WARM;
    const int t_end = t_main + T_CHUNK;

    for (int t0 = t_begin; t0 < t_end; t0 += ROUND) {
        // stage U round: ROUND steps x 64 n (contiguous)
#pragma unroll
        for (int i = 0; i < 2; ++i) {
            int f4 = i * 1024 + tid * 4;
            *(float4*)&Ulds[f4] =
                *(const float4*)&U[ubase + (size_t)t0 * 64 + f4];
        }
        // stage x round: ROUND steps x 32 d
        {
            int f4 = tid * 4;
            int tt = f4 >> 5, dd = f4 & 31;
            *(float4*)&xlds[f4] =
                *(const float4*)&x[xbase + (size_t)(t0 + tt) * D_MODEL + d0 + dd];
        }
        __syncthreads();

        const bool emit = (t0 >= t_main);
        if (emit) {
#pragma unroll 4
            for (int tt = 0; tt < ROUND; ++tt) {
                const v2f* up = (const v2f*)&Ulds[tt * 64 + l * 8];
                float xt = xlds[tt * 32 + g];
                v2f xt2 = {xt, xt};
                v2f y2 = {0.0f, 0.0f};
#pragma unroll
                for (int jp = 0; jp < 4; ++jp) {
                    v2f t = up[jp] * xt2;                              // pk_mul
                    t = __builtin_elementwise_fma(h2[jp], a2[jp], t);  // pk_fma
                    t.x = __builtin_amdgcn_fmed3f(t.x, 0.0f, 1.0f);
                    t.y = __builtin_amdgcn_fmed3f(t.y, 0.0f, 1.0f);
                    h2[jp] = t;
                    y2 = __builtin_elementwise_fma(t, c2[jp], y2);     // pk_fma
                }
                float y = y2.x + y2.y;
                y += __shfl_xor(y, 1);
                y += __shfl_xor(y, 2);
                y += __shfl_xor(y, 4);
                if (l == 0) ylds[tt * 32 + g] = y;
            }
        } else {
            // warm-up: advance h only, no y
#pragma unroll 4
            for (int tt = 0; tt < ROUND; ++tt) {
                const v2f* up = (const v2f*)&Ulds[tt * 64 + l * 8];
                float xt = xlds[tt * 32 + g];
                v2f xt2 = {xt, xt};
#pragma unroll
                for (int jp = 0; jp < 4; ++jp) {
                    v2f t = up[jp] * xt2;
                    t = __builtin_elementwise_fma(h2[jp], a2[jp], t);
                    t.x = __builtin_amdgcn_fmed3f(t.x, 0.0f, 1.0f);
                    t.y = __builtin_amdgcn_fmed3f(t.y, 0.0f, 1.0f);
                    h2[jp] = t;
                }
            }
        }
        __syncthreads();

        if (emit) {
            int f4 = tid * 4;
            int tt = f4 >> 5, dd = f4 & 31;
            *(float4*)&yraw[xbase + (size_t)(t0 + tt) * D_MODEL + d0 + dd] =
                *(const float4*)&ylds[f4];
        }
        // Ulds/xlds rewrite next round is fenced by the post-stage sync;
        // ylds flush-read vs next compute-write is fenced the same way.
    }

    if (c == (SEQ / T_CHUNK) - 1) {
        float4 h0 = make_float4(h2[0].x, h2[0].y, h2[1].x, h2[1].y);
        float4 h1 = make_float4(h2[2].x, h2[2].y, h2[3].x, h2[3].y);
        size_t hoff = ((size_t)b * D_MODEL + d) * 64 + l * 8;
        *(float4*)&hout[hoff] = h0;
        *(float4*)&hout[hoff + 4] = h1;
    }
}

// ---------------------------------------------------------------------------
// Kernel 3: in-place normalize: out = clip(g*y/(sum_d y + eps) + x, 0, 1)
// ---------------------------------------------------------------------------
__global__ __launch_bounds__(256) void norm_kernel(
    const float* __restrict__ x, const float* __restrict__ gs,
    float* __restrict__ y) {
    __shared__ float red[4];
    const int tid = threadIdx.x;
    const size_t base = (size_t)blockIdx.x * D_MODEL;

    float4 yv = *(const float4*)&y[base + tid * 4];
    float s = yv.x + yv.y + yv.z + yv.w;
#pragma unroll
    for (int off = 1; off < 64; off <<= 1) s += __shfl_xor(s, off);
    if ((tid & 63) == 0) red[tid >> 6] = s;
    __syncthreads();
    float tot = red[0] + red[1] + red[2] + red[3];
    float inv = 1.0f / (tot + EPS);

    float4 xv = *(const float4*)&x[base + tid * 4];
    float4 gv = *(const float4*)&gs[tid * 4];
    float4 o;
    o.x = __builtin_amdgcn_fmed3f(fmaf(gv.x * yv.x, inv, xv.x), 0.0f, 1.0f);
    o.y = __builtin_amdgcn_fmed3f(fmaf(gv.y * yv.y, inv, xv.y), 0.0f, 1.0f);
    o.z = __builtin_amdgcn_fmed3f(fmaf(gv.z * yv.z, inv, xv.z), 0.0f, 1.0f);
    o.w = __builtin_amdgcn_fmed3f(fmaf(gv.w * yv.w, inv, xv.w), 0.0f, 1.0f);
    *(float4*)&y[base + tid * 4] = o;
}

// ---------------------------------------------------------------------------
extern "C" void kernel_launch(void* const* d_in, const int* in_sizes, int n_in,
                              void* d_out, int out_size, void* d_ws,
                              size_t ws_size, hipStream_t stream) {
    const float* x     = (const float*)d_in[0];
    const float* A_raw = (const float*)d_in[1];
    const float* B_w   = (const float*)d_in[2];
    const float* C_w   = (const float*)d_in[3];
    const float* gamma = (const float*)d_in[4];

    float* out  = (float*)d_out;
    float* yout = out;                                      // [B,S,D]
    float* hout = out + (size_t)B_BATCH * SEQ * D_MODEL;    // [B,D,N]

    float* ws = (float*)d_ws;
    float* As = ws;                  // 65536
    float* Bt = ws + 65536;          // 65536
    float* Cs = ws + 131072;         // 65536
    float* gs = ws + 196608;         // 1024
    float* U  = ws + 197632;         // B*SEQ*64 = 2097152

    prep_kernel<<<256, 256, 0, stream>>>(A_raw, B_w, C_w, gamma, As, Bt, Cs, gs);
    u_gemm_kernel<<<(B_BATCH * SEQ) / 64, 256, 0, stream>>>(x, Bt, U);
    scan_kernel<<<B_BATCH * (D_MODEL / 32) * (SEQ / T_CHUNK), 256, 0, stream>>>(
        x, U, As, Cs, yout, hout);
    norm_kernel<<<B_BATCH * SEQ, 256, 0, stream>>>(x, gs, yout);
}

// Round 3
// 537.706 us; speedup vs baseline: 1.3442x; 1.0905x over previous
//
#include <hip/hip_runtime.h>

#define B_BATCH 8
#define SEQ 4096
#define D_MODEL 1024
#define D_STATE 64
#define EPS 1e-6f

#define T_CHUNK 512   // time steps per scan block (8 chunks)
#define WARM 64       // redundant warm-up steps; A<=0.7311 => 0.7311^64 ~ 2e-9
#define ROUND 32      // steps staged in LDS per round

typedef float v2f __attribute__((ext_vector_type(2)));

// DPP sum within each 8-lane group; result valid in lane l==7 of each group.
// row_shr within a 16-row: lane 7 and lane 15 accumulate exactly their own
// 8-group (tree identical to the xor-butterfly => bit-identical rounding).
#define DPP_ADD(v, ctrl)                                                    \
    ((v) + __int_as_float(__builtin_amdgcn_update_dpp(                      \
               0, __float_as_int(v), (ctrl), 0xF, 0xF, true)))

__device__ __forceinline__ float sigmoidf(float v) {
    return 1.0f / (1.0f + __expf(-v));
}

// ---------------------------------------------------------------------------
// Kernel 0: apply sigmoids, transpose B_w to [D][N]
// ---------------------------------------------------------------------------
__global__ __launch_bounds__(256) void prep_kernel(
    const float* __restrict__ A_raw, const float* __restrict__ B_w,
    const float* __restrict__ C_w, const float* __restrict__ gamma,
    float* __restrict__ As, float* __restrict__ Bt, float* __restrict__ Cs,
    float* __restrict__ gs) {
    int i = blockIdx.x * 256 + threadIdx.x;   // 0 .. D*N-1
    int d = i >> 6;
    int n = i & 63;
    As[i] = sigmoidf(A_raw[i]);               // [D][N]
    Cs[i] = sigmoidf(C_w[i]);                 // [D][N]
    Bt[i] = sigmoidf(B_w[n * D_MODEL + d]);   // Bt[d][n] = sigmoid(B_w[n][d])
    if (n == 0) gs[d] = sigmoidf(gamma[d]);
}

// ---------------------------------------------------------------------------
// Kernel 1: U[row][n] = sum_d x[row][d] * Bt[d][n]   (row = b*SEQ + t)
// ---------------------------------------------------------------------------
__device__ __forceinline__ void fma4(float av, const float4 bv, float* acc) {
    acc[0] = fmaf(av, bv.x, acc[0]);
    acc[1] = fmaf(av, bv.y, acc[1]);
    acc[2] = fmaf(av, bv.z, acc[2]);
    acc[3] = fmaf(av, bv.w, acc[3]);
}

__global__ __launch_bounds__(256) void u_gemm_kernel(
    const float* __restrict__ x, const float* __restrict__ Bt,
    float* __restrict__ U) {
    __shared__ float xs[64 * 68];
    __shared__ float Bs[64 * 64];
    const int tid = threadIdx.x;
    const int row0 = blockIdx.x * 64;
    const int tr = tid >> 4;
    const int tc = tid & 15;
    float acc[4][4] = {};

    for (int d0 = 0; d0 < D_MODEL; d0 += 64) {
#pragma unroll
        for (int i = 0; i < 4; ++i) {
            int f4 = i * 1024 + tid * 4;
            int r = f4 >> 6, c = f4 & 63;
            float4 v = *(const float4*)&x[(size_t)(row0 + r) * D_MODEL + d0 + c];
            *(float4*)&xs[r * 68 + c] = v;
        }
#pragma unroll
        for (int i = 0; i < 4; ++i) {
            int f4 = i * 1024 + tid * 4;
            *(float4*)&Bs[f4] = *(const float4*)&Bt[d0 * 64 + f4];
        }
        __syncthreads();
#pragma unroll
        for (int dd = 0; dd < 64; dd += 4) {
            float4 b0 = *(const float4*)&Bs[(dd + 0) * 64 + tc * 4];
            float4 b1 = *(const float4*)&Bs[(dd + 1) * 64 + tc * 4];
            float4 b2 = *(const float4*)&Bs[(dd + 2) * 64 + tc * 4];
            float4 b3 = *(const float4*)&Bs[(dd + 3) * 64 + tc * 4];
#pragma unroll
            for (int i = 0; i < 4; ++i) {
                float4 a = *(const float4*)&xs[(tr * 4 + i) * 68 + dd];
                fma4(a.x, b0, acc[i]);
                fma4(a.y, b1, acc[i]);
                fma4(a.z, b2, acc[i]);
                fma4(a.w, b3, acc[i]);
            }
        }
        __syncthreads();
    }
#pragma unroll
    for (int i = 0; i < 4; ++i) {
        float4 v = make_float4(acc[i][0], acc[i][1], acc[i][2], acc[i][3]);
        *(float4*)&U[(size_t)(row0 + tr * 4 + i) * 64 + tc * 4] = v;
    }
}

// ---------------------------------------------------------------------------
// Kernel 2: time-split scan. Block = (b, 64-d chunk, t-chunk of 512).
// 8 lanes per d, 8 n/lane as 4 float2 pairs (v_pk_mul/fma_f32).
// EACH THREAD OWNS TWO d's (d0+g and d0+32+g) sharing one U slice read:
// round-2 analysis showed the per-CU DS pipe is the bottleneck and the
// 2x ds_read_b128 of U dominates it -> amortize over 2 d (halves per-d DS).
// y-reduction uses DPP row_shr adds (pure VALU, zero DS ops); writer l==7.
// Control flow stays data-INDEPENDENT (round-1 lesson: lockstep progress is
// what lets L3 absorb the cross-block U reuse).
// Each t-chunk (except the first) redundantly recomputes WARM steps from
// h=0; contraction (A<=0.7311) kills the error.
// Emits UNNORMALIZED y into yraw; last chunk emits h_final.
// ---------------------------------------------------------------------------
__global__ __launch_bounds__(256, 4) void scan_kernel(
    const float* __restrict__ x, const float* __restrict__ U,
    const float* __restrict__ As, const float* __restrict__ Cs,
    float* __restrict__ yraw, float* __restrict__ hout) {
    __shared__ float Ulds[ROUND * 64];   // 8 KB
    __shared__ float xlds[ROUND * 64];   // 8 KB
    __shared__ float ylds[ROUND * 64];   // 8 KB
    const int tid = threadIdx.x;
    const int c = blockIdx.x & 7;                  // t-chunk
    const int d0 = ((blockIdx.x >> 3) & 15) * 64;  // d-chunk (64 wide)
    const int b = blockIdx.x >> 7;                 // batch
    const int g = tid >> 3;   // 0..31
    const int l = tid & 7;    // 0..7  -> n = l*8 .. l*8+7
    const int da = d0 + g;
    const int db = d0 + 32 + g;

    v2f hA[4], aA[4], cA[4], hB[4], aB[4], cB[4];
    {
        const v2f* apA = (const v2f*)&As[da * 64 + l * 8];
        const v2f* cpA = (const v2f*)&Cs[da * 64 + l * 8];
        const v2f* apB = (const v2f*)&As[db * 64 + l * 8];
        const v2f* cpB = (const v2f*)&Cs[db * 64 + l * 8];
#pragma unroll
        for (int jp = 0; jp < 4; ++jp) {
            aA[jp] = apA[jp]; cA[jp] = cpA[jp];
            aB[jp] = apB[jp]; cB[jp] = cpB[jp];
            hA[jp] = (v2f){0.0f, 0.0f};
            hB[jp] = (v2f){0.0f, 0.0f};
        }
    }

    const size_t xbase = (size_t)b * SEQ * D_MODEL;
    const size_t ubase = (size_t)b * SEQ * 64;
    const int t_main = c * T_CHUNK;
    const int t_begin = (c == 0) ? 0 : t_main - WARM;
    const int t_end = t_main + T_CHUNK;

    for (int t0 = t_begin; t0 < t_end; t0 += ROUND) {
        // stage U round: ROUND steps x 64 n (contiguous)
#pragma unroll
        for (int i = 0; i < 2; ++i) {
            int f4 = i * 1024 + tid * 4;
            *(float4*)&Ulds[f4] =
                *(const float4*)&U[ubase + (size_t)t0 * 64 + f4];
        }
        // stage x round: ROUND steps x 64 d
#pragma unroll
        for (int i = 0; i < 2; ++i) {
            int f4 = i * 1024 + tid * 4;
            int tt = f4 >> 6, dd = f4 & 63;
            *(float4*)&xlds[f4] =
                *(const float4*)&x[xbase + (size_t)(t0 + tt) * D_MODEL + d0 + dd];
        }
        __syncthreads();

        const bool emit = (t0 >= t_main);
        if (emit) {
#pragma unroll 4
            for (int tt = 0; tt < ROUND; ++tt) {
                const v2f* up = (const v2f*)&Ulds[tt * 64 + l * 8];
                float xa = xlds[tt * 64 + g];
                float xb = xlds[tt * 64 + 32 + g];
                v2f xa2 = {xa, xa}, xb2 = {xb, xb};
                v2f ya = {0.0f, 0.0f}, yb = {0.0f, 0.0f};
#pragma unroll
                for (int jp = 0; jp < 4; ++jp) {
                    v2f u = up[jp];
                    v2f tA = __builtin_elementwise_fma(hA[jp], aA[jp], u * xa2);
                    v2f tB = __builtin_elementwise_fma(hB[jp], aB[jp], u * xb2);
                    tA.x = __builtin_amdgcn_fmed3f(tA.x, 0.0f, 1.0f);
                    tA.y = __builtin_amdgcn_fmed3f(tA.y, 0.0f, 1.0f);
                    tB.x = __builtin_amdgcn_fmed3f(tB.x, 0.0f, 1.0f);
                    tB.y = __builtin_amdgcn_fmed3f(tB.y, 0.0f, 1.0f);
                    hA[jp] = tA;
                    hB[jp] = tB;
                    ya = __builtin_elementwise_fma(tA, cA[jp], ya);
                    yb = __builtin_elementwise_fma(tB, cB[jp], yb);
                }
                float sa = ya.x + ya.y;
                float sb = yb.x + yb.y;
                sa = DPP_ADD(sa, 0x111);   // row_shr:1
                sa = DPP_ADD(sa, 0x112);   // row_shr:2
                sa = DPP_ADD(sa, 0x114);   // row_shr:4
                sb = DPP_ADD(sb, 0x111);
                sb = DPP_ADD(sb, 0x112);
                sb = DPP_ADD(sb, 0x114);
                if (l == 7) {
                    ylds[tt * 64 + g] = sa;
                    ylds[tt * 64 + 32 + g] = sb;
                }
            }
        } else {
            // warm-up: advance h only, no y
#pragma unroll 4
            for (int tt = 0; tt < ROUND; ++tt) {
                const v2f* up = (const v2f*)&Ulds[tt * 64 + l * 8];
                float xa = xlds[tt * 64 + g];
                float xb = xlds[tt * 64 + 32 + g];
                v2f xa2 = {xa, xa}, xb2 = {xb, xb};
#pragma unroll
                for (int jp = 0; jp < 4; ++jp) {
                    v2f u = up[jp];
                    v2f tA = __builtin_elementwise_fma(hA[jp], aA[jp], u * xa2);
                    v2f tB = __builtin_elementwise_fma(hB[jp], aB[jp], u * xb2);
                    tA.x = __builtin_amdgcn_fmed3f(tA.x, 0.0f, 1.0f);
                    tA.y = __builtin_amdgcn_fmed3f(tA.y, 0.0f, 1.0f);
                    tB.x = __builtin_amdgcn_fmed3f(tB.x, 0.0f, 1.0f);
                    tB.y = __builtin_amdgcn_fmed3f(tB.y, 0.0f, 1.0f);
                    hA[jp] = tA;
                    hB[jp] = tB;
                }
            }
        }
        __syncthreads();

        if (emit) {
#pragma unroll
            for (int i = 0; i < 2; ++i) {
                int f4 = i * 1024 + tid * 4;
                int tt = f4 >> 6, dd = f4 & 63;
                *(float4*)&yraw[xbase + (size_t)(t0 + tt) * D_MODEL + d0 + dd] =
                    *(const float4*)&ylds[f4];
            }
        }
        // Ulds/xlds rewrite next round is fenced by the post-stage sync;
        // ylds flush-read vs next compute-write is fenced the same way.
    }

    if (c == (SEQ / T_CHUNK) - 1) {
        float4 h0 = make_float4(hA[0].x, hA[0].y, hA[1].x, hA[1].y);
        float4 h1 = make_float4(hA[2].x, hA[2].y, hA[3].x, hA[3].y);
        size_t hoffA = ((size_t)b * D_MODEL + da) * 64 + l * 8;
        *(float4*)&hout[hoffA] = h0;
        *(float4*)&hout[hoffA + 4] = h1;
        float4 h2 = make_float4(hB[0].x, hB[0].y, hB[1].x, hB[1].y);
        float4 h3 = make_float4(hB[2].x, hB[2].y, hB[3].x, hB[3].y);
        size_t hoffB = ((size_t)b * D_MODEL + db) * 64 + l * 8;
        *(float4*)&hout[hoffB] = h2;
        *(float4*)&hout[hoffB + 4] = h3;
    }
}

// ---------------------------------------------------------------------------
// Kernel 3: in-place normalize: out = clip(g*y/(sum_d y + eps) + x, 0, 1)
// ---------------------------------------------------------------------------
__global__ __launch_bounds__(256) void norm_kernel(
    const float* __restrict__ x, const float* __restrict__ gs,
    float* __restrict__ y) {
    __shared__ float red[4];
    const int tid = threadIdx.x;
    const size_t base = (size_t)blockIdx.x * D_MODEL;

    float4 yv = *(const float4*)&y[base + tid * 4];
    float s = yv.x + yv.y + yv.z + yv.w;
#pragma unroll
    for (int off = 1; off < 64; off <<= 1) s += __shfl_xor(s, off);
    if ((tid & 63) == 0) red[tid >> 6] = s;
    __syncthreads();
    float tot = red[0] + red[1] + red[2] + red[3];
    float inv = 1.0f / (tot + EPS);

    float4 xv = *(const float4*)&x[base + tid * 4];
    float4 gv = *(const float4*)&gs[tid * 4];
    float4 o;
    o.x = __builtin_amdgcn_fmed3f(fmaf(gv.x * yv.x, inv, xv.x), 0.0f, 1.0f);
    o.y = __builtin_amdgcn_fmed3f(fmaf(gv.y * yv.y, inv, xv.y), 0.0f, 1.0f);
    o.z = __builtin_amdgcn_fmed3f(fmaf(gv.z * yv.z, inv, xv.z), 0.0f, 1.0f);
    o.w = __builtin_amdgcn_fmed3f(fmaf(gv.w * yv.w, inv, xv.w), 0.0f, 1.0f);
    *(float4*)&y[base + tid * 4] = o;
}

// ---------------------------------------------------------------------------
extern "C" void kernel_launch(void* const* d_in, const int* in_sizes, int n_in,
                              void* d_out, int out_size, void* d_ws,
                              size_t ws_size, hipStream_t stream) {
    const float* x     = (const float*)d_in[0];
    const float* A_raw = (const float*)d_in[1];
    const float* B_w   = (const float*)d_in[2];
    const float* C_w   = (const float*)d_in[3];
    const float* gamma = (const float*)d_in[4];

    float* out  = (float*)d_out;
    float* yout = out;                                      // [B,S,D]
    float* hout = out + (size_t)B_BATCH * SEQ * D_MODEL;    // [B,D,N]

    float* ws = (float*)d_ws;
    float* As = ws;                  // 65536
    float* Bt = ws + 65536;          // 65536
    float* Cs = ws + 131072;         // 65536
    float* gs = ws + 196608;         // 1024
    float* U  = ws + 197632;         // B*SEQ*64 = 2097152

    prep_kernel<<<256, 256, 0, stream>>>(A_raw, B_w, C_w, gamma, As, Bt, Cs, gs);
    u_gemm_kernel<<<(B_BATCH * SEQ) / 64, 256, 0, stream>>>(x, Bt, U);
    scan_kernel<<<B_BATCH * (D_MODEL / 64) * (SEQ / T_CHUNK), 256, 0, stream>>>(
        x, U, As, Cs, yout, hout);
    norm_kernel<<<B_BATCH * SEQ, 256, 0, stream>>>(x, gs, yout);
}

// Round 4
// 527.044 us; speedup vs baseline: 1.3714x; 1.0202x over previous
//
#include <hip/hip_runtime.h>

#define B_BATCH 8
#define SEQ 4096
#define D_MODEL 1024
#define D_STATE 64
#define EPS 1e-6f

#define T_CHUNK 512   // time steps per scan block (8 chunks)
#define WARM 64       // redundant warm-up steps; A<=0.7311 => 0.7311^64 ~ 2e-9
#define ROUND 32      // steps staged in LDS per round

typedef float v2f __attribute__((ext_vector_type(2)));
typedef short bf16x8 __attribute__((ext_vector_type(8)));
typedef float f32x4 __attribute__((ext_vector_type(4)));
typedef unsigned short ushortT;
typedef ushortT u16x8 __attribute__((ext_vector_type(8)));

// DPP sum within each 8-lane group; result valid in lane l==7 of each group.
#define DPP_ADD(v, ctrl)                                                    \
    ((v) + __int_as_float(__builtin_amdgcn_update_dpp(                      \
               0, __float_as_int(v), (ctrl), 0xF, 0xF, true)))

__device__ __forceinline__ float sigmoidf(float v) {
    return 1.0f / (1.0f + __expf(-v));
}

// fp32 -> bf16 round-to-nearest-even (inputs here are never NaN)
__device__ __forceinline__ ushortT f2bf(float f) {
    unsigned int u = __float_as_uint(f);
    u += 0x7FFFu + ((u >> 16) & 1u);
    return (ushortT)(u >> 16);
}

// ---------------------------------------------------------------------------
// Kernel 0: apply sigmoids. Btbf[n][d] = bf16(sigmoid(B_w[n][d])) — B_w is
// already [N][D] row-major, which IS the B^T operand layout MFMA wants.
// ---------------------------------------------------------------------------
__global__ __launch_bounds__(256) void prep_kernel(
    const float* __restrict__ A_raw, const float* __restrict__ B_w,
    const float* __restrict__ C_w, const float* __restrict__ gamma,
    float* __restrict__ As, ushortT* __restrict__ Btbf,
    float* __restrict__ Cs, float* __restrict__ gs) {
    int i = blockIdx.x * 256 + threadIdx.x;   // 0 .. D*N-1
    int d = i >> 6;
    int n = i & 63;
    As[i] = sigmoidf(A_raw[i]);               // [D][N]
    Cs[i] = sigmoidf(C_w[i]);                 // [D][N]
    Btbf[i] = f2bf(sigmoidf(B_w[i]));         // [N][D] row-major (i = n*D + d)
    if (n == 0) gs[d] = sigmoidf(gamma[d]);
}

// ---------------------------------------------------------------------------
// Kernel 1: U[row][n] = sum_d x[row][d] * sigmoid(B_w)[n][d]  via bf16 MFMA.
// Round-3 analysis: the fp32 version was DS-pipe-bound (~170 us, 8x
// ds_read_b128 per 64 fma on the shared per-CU DS pipe). MFMA needs 16x
// fewer DS reads per FLOP. Block = 64 rows x 64 n, 4 waves (wave w = rows
// 16w..16w+15); K-step 32. x cast to bf16 in staging (RNE); products bf16,
// accumulate fp32 => |dU| ~ 0.03 on U~256, which the scan's saturating
// state update tolerates (see scan comments).
// Fragment layouts per guide (m89-verified): A: lane(r+16q) holds
// A[r][8q..8q+7]; B: lane(c+16q) holds B^T[c][8q..8q+7]; D: col=lane&15,
// row=(lane>>4)*4+reg.
// ---------------------------------------------------------------------------
__global__ __launch_bounds__(256) void u_gemm_kernel(
    const float* __restrict__ x, const ushortT* __restrict__ Btbf,
    float* __restrict__ U) {
    // stride 40 ushorts (80 B): keeps b128 reads 16B-aligned, rows land on
    // distinct-or-2-way banks (2-way is free, m136)
    __shared__ __align__(16) ushortT xs[64 * 40];
    __shared__ __align__(16) ushortT Bs[64 * 40];
    const int tid = threadIdx.x;
    const int r0 = blockIdx.x * 64;
    const int w = tid >> 6;          // wave 0..3
    const int l = tid & 63;          // lane
    const int srow = tid >> 2;       // staging row 0..63
    const int scol = (tid & 3) * 8;  // staging col {0,8,16,24}

    const int a_off = (w * 16 + (l & 15)) * 40 + (l >> 4) * 8;
    const int b_off = (l & 15) * 40 + (l >> 4) * 8;   // + n0*40

    f32x4 acc0 = {0.f, 0.f, 0.f, 0.f};
    f32x4 acc1 = {0.f, 0.f, 0.f, 0.f};
    f32x4 acc2 = {0.f, 0.f, 0.f, 0.f};
    f32x4 acc3 = {0.f, 0.f, 0.f, 0.f};

    const size_t xrow = (size_t)(r0 + srow) * D_MODEL;
    // prologue: prefetch k-step 0
    float4 xv0 = *(const float4*)&x[xrow + scol];
    float4 xv1 = *(const float4*)&x[xrow + scol + 4];
    u16x8 bv = *(const u16x8*)&Btbf[srow * D_MODEL + scol];

    for (int ks = 0; ks < 32; ++ks) {
        u16x8 xw;
        xw[0] = f2bf(xv0.x); xw[1] = f2bf(xv0.y);
        xw[2] = f2bf(xv0.z); xw[3] = f2bf(xv0.w);
        xw[4] = f2bf(xv1.x); xw[5] = f2bf(xv1.y);
        xw[6] = f2bf(xv1.z); xw[7] = f2bf(xv1.w);
        *(u16x8*)&xs[srow * 40 + scol] = xw;
        *(u16x8*)&Bs[srow * 40 + scol] = bv;
        if (ks + 1 < 32) {   // prefetch next k-step; latency hides under MFMA
            int k0 = (ks + 1) * 32;
            xv0 = *(const float4*)&x[xrow + k0 + scol];
            xv1 = *(const float4*)&x[xrow + k0 + scol + 4];
            bv = *(const u16x8*)&Btbf[srow * D_MODEL + k0 + scol];
        }
        __syncthreads();
        bf16x8 a  = *(const bf16x8*)&xs[a_off];
        bf16x8 b0 = *(const bf16x8*)&Bs[b_off];
        bf16x8 b1 = *(const bf16x8*)&Bs[b_off + 16 * 40];
        bf16x8 b2 = *(const bf16x8*)&Bs[b_off + 32 * 40];
        bf16x8 b3 = *(const bf16x8*)&Bs[b_off + 48 * 40];
        acc0 = __builtin_amdgcn_mfma_f32_16x16x32_bf16(a, b0, acc0, 0, 0, 0);
        acc1 = __builtin_amdgcn_mfma_f32_16x16x32_bf16(a, b1, acc1, 0, 0, 0);
        acc2 = __builtin_amdgcn_mfma_f32_16x16x32_bf16(a, b2, acc2, 0, 0, 0);
        acc3 = __builtin_amdgcn_mfma_f32_16x16x32_bf16(a, b3, acc3, 0, 0, 0);
        __syncthreads();   // protect in-place LDS rewrite next iteration
    }

    const int c16 = l & 15;
    const int rb = (l >> 4) * 4;
#pragma unroll
    for (int i = 0; i < 4; ++i) {
        size_t row = (size_t)(r0 + w * 16 + rb + i);
        U[row * 64 +  0 + c16] = acc0[i];
        U[row * 64 + 16 + c16] = acc1[i];
        U[row * 64 + 32 + c16] = acc2[i];
        U[row * 64 + 48 + c16] = acc3[i];
    }
}

// ---------------------------------------------------------------------------
// Kernel 2: time-split scan. Block = (b, 64-d chunk, t-chunk of 512).
// 8 lanes per d, 8 n/lane as 4 float2 pairs (v_pk_mul/fma_f32).
// EACH THREAD OWNS TWO d's (d0+g and d0+32+g) sharing one U slice read
// (round-2: DS pipe was the bottleneck; U read amortized over 2 d).
// y-reduction uses DPP row_shr adds (pure VALU, zero DS ops); writer l==7.
// Control flow stays data-INDEPENDENT (round-1 lesson: lockstep progress is
// what lets L3 absorb the cross-block U reuse).
// Each t-chunk (except the first) redundantly recomputes WARM steps from
// h=0; contraction (A<=0.7311) kills the error. Note the state update
// saturates (h=1 exactly) whenever u*x>=1, which also absorbs the bf16
// rounding of U from u_gemm (non-saturated steps see |d(u*x)| <= 1.2e-4).
// Emits UNNORMALIZED y into yraw; last chunk emits h_final.
// ---------------------------------------------------------------------------
__global__ __launch_bounds__(256, 4) void scan_kernel(
    const float* __restrict__ x, const float* __restrict__ U,
    const float* __restrict__ As, const float* __restrict__ Cs,
    float* __restrict__ yraw, float* __restrict__ hout) {
    __shared__ float Ulds[ROUND * 64];   // 8 KB
    __shared__ float xlds[ROUND * 64];   // 8 KB
    __shared__ float ylds[ROUND * 64];   // 8 KB
    const int tid = threadIdx.x;
    const int c = blockIdx.x & 7;                  // t-chunk
    const int d0 = ((blockIdx.x >> 3) & 15) * 64;  // d-chunk (64 wide)
    const int b = blockIdx.x >> 7;                 // batch
    const int g = tid >> 3;   // 0..31
    const int l = tid & 7;    // 0..7  -> n = l*8 .. l*8+7
    const int da = d0 + g;
    const int db = d0 + 32 + g;

    v2f hA[4], aA[4], cA[4], hB[4], aB[4], cB[4];
    {
        const v2f* apA = (const v2f*)&As[da * 64 + l * 8];
        const v2f* cpA = (const v2f*)&Cs[da * 64 + l * 8];
        const v2f* apB = (const v2f*)&As[db * 64 + l * 8];
        const v2f* cpB = (const v2f*)&Cs[db * 64 + l * 8];
#pragma unroll
        for (int jp = 0; jp < 4; ++jp) {
            aA[jp] = apA[jp]; cA[jp] = cpA[jp];
            aB[jp] = apB[jp]; cB[jp] = cpB[jp];
            hA[jp] = (v2f){0.0f, 0.0f};
            hB[jp] = (v2f){0.0f, 0.0f};
        }
    }

    const size_t xbase = (size_t)b * SEQ * D_MODEL;
    const size_t ubase = (size_t)b * SEQ * 64;
    const int t_main = c * T_CHUNK;
    const int t_begin = (c == 0) ? 0 : t_main - WARM;
    const int t_end = t_main + T_CHUNK;

    for (int t0 = t_begin; t0 < t_end; t0 += ROUND) {
        // stage U round: ROUND steps x 64 n (contiguous)
#pragma unroll
        for (int i = 0; i < 2; ++i) {
            int f4 = i * 1024 + tid * 4;
            *(float4*)&Ulds[f4] =
                *(const float4*)&U[ubase + (size_t)t0 * 64 + f4];
        }
        // stage x round: ROUND steps x 64 d
#pragma unroll
        for (int i = 0; i < 2; ++i) {
            int f4 = i * 1024 + tid * 4;
            int tt = f4 >> 6, dd = f4 & 63;
            *(float4*)&xlds[f4] =
                *(const float4*)&x[xbase + (size_t)(t0 + tt) * D_MODEL + d0 + dd];
        }
        __syncthreads();

        const bool emit = (t0 >= t_main);
        if (emit) {
#pragma unroll 4
            for (int tt = 0; tt < ROUND; ++tt) {
                const v2f* up = (const v2f*)&Ulds[tt * 64 + l * 8];
                float xa = xlds[tt * 64 + g];
                float xb = xlds[tt * 64 + 32 + g];
                v2f xa2 = {xa, xa}, xb2 = {xb, xb};
                v2f ya = {0.0f, 0.0f}, yb = {0.0f, 0.0f};
#pragma unroll
                for (int jp = 0; jp < 4; ++jp) {
                    v2f u = up[jp];
                    v2f tA = __builtin_elementwise_fma(hA[jp], aA[jp], u * xa2);
                    v2f tB = __builtin_elementwise_fma(hB[jp], aB[jp], u * xb2);
                    tA.x = __builtin_amdgcn_fmed3f(tA.x, 0.0f, 1.0f);
                    tA.y = __builtin_amdgcn_fmed3f(tA.y, 0.0f, 1.0f);
                    tB.x = __builtin_amdgcn_fmed3f(tB.x, 0.0f, 1.0f);
                    tB.y = __builtin_amdgcn_fmed3f(tB.y, 0.0f, 1.0f);
                    hA[jp] = tA;
                    hB[jp] = tB;
                    ya = __builtin_elementwise_fma(tA, cA[jp], ya);
                    yb = __builtin_elementwise_fma(tB, cB[jp], yb);
                }
                float sa = ya.x + ya.y;
                float sb = yb.x + yb.y;
                sa = DPP_ADD(sa, 0x111);   // row_shr:1
                sa = DPP_ADD(sa, 0x112);   // row_shr:2
                sa = DPP_ADD(sa, 0x114);   // row_shr:4
                sb = DPP_ADD(sb, 0x111);
                sb = DPP_ADD(sb, 0x112);
                sb = DPP_ADD(sb, 0x114);
                if (l == 7) {
                    ylds[tt * 64 + g] = sa;
                    ylds[tt * 64 + 32 + g] = sb;
                }
            }
        } else {
            // warm-up: advance h only, no y
#pragma unroll 4
            for (int tt = 0; tt < ROUND; ++tt) {
                const v2f* up = (const v2f*)&Ulds[tt * 64 + l * 8];
                float xa = xlds[tt * 64 + g];
                float xb = xlds[tt * 64 + 32 + g];
                v2f xa2 = {xa, xa}, xb2 = {xb, xb};
#pragma unroll
                for (int jp = 0; jp < 4; ++jp) {
                    v2f u = up[jp];
                    v2f tA = __builtin_elementwise_fma(hA[jp], aA[jp], u * xa2);
                    v2f tB = __builtin_elementwise_fma(hB[jp], aB[jp], u * xb2);
                    tA.x = __builtin_amdgcn_fmed3f(tA.x, 0.0f, 1.0f);
                    tA.y = __builtin_amdgcn_fmed3f(tA.y, 0.0f, 1.0f);
                    tB.x = __builtin_amdgcn_fmed3f(tB.x, 0.0f, 1.0f);
                    tB.y = __builtin_amdgcn_fmed3f(tB.y, 0.0f, 1.0f);
                    hA[jp] = tA;
                    hB[jp] = tB;
                }
            }
        }
        __syncthreads();

        if (emit) {
#pragma unroll
            for (int i = 0; i < 2; ++i) {
                int f4 = i * 1024 + tid * 4;
                int tt = f4 >> 6, dd = f4 & 63;
                *(float4*)&yraw[xbase + (size_t)(t0 + tt) * D_MODEL + d0 + dd] =
                    *(const float4*)&ylds[f4];
            }
        }
    }

    if (c == (SEQ / T_CHUNK) - 1) {
        float4 h0 = make_float4(hA[0].x, hA[0].y, hA[1].x, hA[1].y);
        float4 h1 = make_float4(hA[2].x, hA[2].y, hA[3].x, hA[3].y);
        size_t hoffA = ((size_t)b * D_MODEL + da) * 64 + l * 8;
        *(float4*)&hout[hoffA] = h0;
        *(float4*)&hout[hoffA + 4] = h1;
        float4 h2 = make_float4(hB[0].x, hB[0].y, hB[1].x, hB[1].y);
        float4 h3 = make_float4(hB[2].x, hB[2].y, hB[3].x, hB[3].y);
        size_t hoffB = ((size_t)b * D_MODEL + db) * 64 + l * 8;
        *(float4*)&hout[hoffB] = h2;
        *(float4*)&hout[hoffB + 4] = h3;
    }
}

// ---------------------------------------------------------------------------
// Kernel 3: in-place normalize: out = clip(g*y/(sum_d y + eps) + x, 0, 1)
// ---------------------------------------------------------------------------
__global__ __launch_bounds__(256) void norm_kernel(
    const float* __restrict__ x, const float* __restrict__ gs,
    float* __restrict__ y) {
    __shared__ float red[4];
    const int tid = threadIdx.x;
    const size_t base = (size_t)blockIdx.x * D_MODEL;

    float4 yv = *(const float4*)&y[base + tid * 4];
    float s = yv.x + yv.y + yv.z + yv.w;
#pragma unroll
    for (int off = 1; off < 64; off <<= 1) s += __shfl_xor(s, off);
    if ((tid & 63) == 0) red[tid >> 6] = s;
    __syncthreads();
    float tot = red[0] + red[1] + red[2] + red[3];
    float inv = 1.0f / (tot + EPS);

    float4 xv = *(const float4*)&x[base + tid * 4];
    float4 gv = *(const float4*)&gs[tid * 4];
    float4 o;
    o.x = __builtin_amdgcn_fmed3f(fmaf(gv.x * yv.x, inv, xv.x), 0.0f, 1.0f);
    o.y = __builtin_amdgcn_fmed3f(fmaf(gv.y * yv.y, inv, xv.y), 0.0f, 1.0f);
    o.z = __builtin_amdgcn_fmed3f(fmaf(gv.z * yv.z, inv, xv.z), 0.0f, 1.0f);
    o.w = __builtin_amdgcn_fmed3f(fmaf(gv.w * yv.w, inv, xv.w), 0.0f, 1.0f);
    *(float4*)&y[base + tid * 4] = o;
}

// ---------------------------------------------------------------------------
extern "C" void kernel_launch(void* const* d_in, const int* in_sizes, int n_in,
                              void* d_out, int out_size, void* d_ws,
                              size_t ws_size, hipStream_t stream) {
    const float* x     = (const float*)d_in[0];
    const float* A_raw = (const float*)d_in[1];
    const float* B_w   = (const float*)d_in[2];
    const float* C_w   = (const float*)d_in[3];
    const float* gamma = (const float*)d_in[4];

    float* out  = (float*)d_out;
    float* yout = out;                                      // [B,S,D]
    float* hout = out + (size_t)B_BATCH * SEQ * D_MODEL;    // [B,D,N]

    float* ws = (float*)d_ws;
    float* As      = ws;                          // 65536 floats
    ushortT* Btbf  = (ushortT*)(ws + 65536);      // 65536 ushorts (in old slot)
    float* Cs      = ws + 131072;                 // 65536 floats
    float* gs      = ws + 196608;                 // 1024 floats
    float* U       = ws + 197632;                 // B*SEQ*64 = 2097152 floats

    prep_kernel<<<256, 256, 0, stream>>>(A_raw, B_w, C_w, gamma, As, Btbf, Cs, gs);
    u_gemm_kernel<<<(B_BATCH * SEQ) / 64, 256, 0, stream>>>(x, Btbf, U);
    scan_kernel<<<B_BATCH * (D_MODEL / 64) * (SEQ / T_CHUNK), 256, 0, stream>>>(
        x, U, As, Cs, yout, hout);
    norm_kernel<<<B_BATCH * SEQ, 256, 0, stream>>>(x, gs, yout);
}